// Round 12
// baseline (591.074 us; speedup 1.0000x reference)
//
#include <hip/hip_runtime.h>
#include <hip/hip_fp16.h>

// DEQ classifier, 32x32x16 MFMA, spill-free + bank-balanced (BIJECTIVE swizzle).
// One block per image (1024 x 256 threads, 4 waves; wave owns 8 output rows
// as two N-groups of 4). LDS: two planes of 8-channel f16 pixel bundles
// (16 B) on a 36-row x 37-bundle-pitch zero-padded grid.
//   swizzle: px(x) = x ^ ((x>>3)&3)   -- intra-row PERMUTATION of [0,36)
//   bofs(y,x) = (y*37 + px(x)) * 16   -- bijective by construction
//   bank quad = (5y + px(x)) & 7 (37 = 5 mod 8):
//     - 8 ax anchors (x stride 4) -> px hits all 8 quads (enumerated)
//     - 4 ry rows -> +{0,5,2,7} shifts
//   => every wave64 ds_read_b128 is 8-lanes-per-quad balanced (minimum cycles).
//   (R11's ((y*37+x)*16)^((x&24)<<1) ALIASED: XOR of bundle-index low bits is
//    not a permutation when the index mixes y and x -- Rule #21.)
//   zxb: [z0..z4, img0..2]    hbb: [h0..h5, 0, 0]
// Conv as MFMA 32x32x16:
//   A[32 rows = dx*8+oc][16 k]  : weights in VGPRs (cw1: 20x4 dw; cw2: 20x3 dw
//                                 -- ch6/7 dword is always 0, not stored)
//   B[16 k][32 cols = ry*8+ax]  : pixel bundle at (ybase+ry+ty, 4ax+tx), 1 b128/lane
//   k = tp*8+ch, tap = 2c+tp over 5x8 window (ty=c>>2, tx=2(c&3)+tp); 20 chunks.
//   D: col=lane&31=(ry,ax), row=(reg&3)+8*(reg>>2)+4*(lane>>5) = dx*8+oc
// GroupNorm: conv1 acc kept in regs across B1; normalized h written after the
// fold -> zero pads stay exact, conv2 uses plain weights + plain bias.
// Register budget: launch_bounds(256,1) -> cap 256; est live ~220 -> no spill.
// Tripwire: FETCH_SIZE must stay ~7 MB; spill shows as FETCH/WRITE blowup.

typedef _Float16 half8 __attribute__((ext_vector_type(8)));
typedef float f32x16 __attribute__((ext_vector_type(16)));

#define PIT   37                 // bundles per row
#define ROWB  (PIT * 16)         // 592 bytes per row
#define PLDW  (36 * PIT * 4)     // 5328 dwords per plane

__device__ __forceinline__ unsigned pk2(float a, float b) {
    __half2 h = __float22half2_rn(make_float2(a, b));
    return *reinterpret_cast<unsigned*>(&h);
}
__device__ __forceinline__ float2 up2(unsigned u) {
    __half2 h = *reinterpret_cast<__half2*>(&u);
    return __half22float2(h);
}
__device__ __forceinline__ float lrelu(float x) { return fmaxf(x, 0.01f * x); }
__device__ __forceinline__ int pxs(int x) { return x ^ ((x >> 3) & 3); }   // bijection on [0,36)
__device__ __forceinline__ int bofs(int y, int x) {
    return (y * PIT + pxs(x)) * 16;
}
__device__ __forceinline__ int swzx(int x) { return pxs(x) * 16; }

// ---- prep: 32x32 A-fragments ----
// ws[0..5119]      : conv1 A-frags, 20 chunks x 64 lanes x 4 dw
//   lane l: m=l&31 (dx=m>>3, oc=m&7), tp=l>>5; tap=2c+tp (ty=tap>>3, tx=tap&7)
//   elem j = ch j: w1[oc][ch][ty][tx-dx], 0 if oc>=6 or tx-dx not in [0,5)
// ws[5120..7679]   : conv2 A-frags ch0..3, 20 chunks x 64 lanes x 2 dw (uint2)
// ws[7680..8959]   : conv2 A-frags ch4..5, 20 chunks x 64 lanes x 1 dw
__global__ void pack_weights(const float* __restrict__ w1,
                             const float* __restrict__ w2,
                             unsigned* __restrict__ ws)
{
    int t = blockIdx.x * 256 + threadIdx.x;
    if (t < 1280) {
        int c = t >> 6, l = t & 63;
        int m = l & 31, tp = l >> 5;
        int dx = m >> 3, oc = m & 7;
        int tap = 2 * c + tp, ty = tap >> 3, tx = tap & 7, kx = tx - dx;
        unsigned q[4];
        #pragma unroll
        for (int d = 0; d < 4; ++d) {
            float v0 = 0.f, v1 = 0.f;
            if (oc < 6 && kx >= 0 && kx < 5) {
                v0 = w1[((oc * 8 + 2 * d) * 5 + ty) * 5 + kx];
                v1 = w1[((oc * 8 + 2 * d + 1) * 5 + ty) * 5 + kx];
            }
            q[d] = pk2(v0, v1);
        }
        *(uint4*)&ws[t * 4] = make_uint4(q[0], q[1], q[2], q[3]);
    } else if (t < 2560) {
        int u = t - 1280;
        int c = u >> 6, l = u & 63;
        int m = l & 31, tp = l >> 5;
        int dx = m >> 3, oc = m & 7;
        int tap = 2 * c + tp, ty = tap >> 3, tx = tap & 7, kx = tx - dx;
        unsigned q[3];
        #pragma unroll
        for (int d = 0; d < 3; ++d) {
            float v0 = 0.f, v1 = 0.f;
            if (oc < 5 && kx >= 0 && kx < 5) {
                v0 = w2[((oc * 6 + 2 * d) * 5 + ty) * 5 + kx];
                if (2 * d + 1 < 6) v1 = w2[((oc * 6 + 2 * d + 1) * 5 + ty) * 5 + kx];
            }
            q[d] = pk2(v0, v1);
        }
        *(uint2*)&ws[5120 + u * 2] = make_uint2(q[0], q[1]);
        ws[7680 + u] = q[2];
    }
}

__global__ __launch_bounds__(256, 1)
void deq_kernel(const float* __restrict__ image,
                const unsigned* __restrict__ wks,
                const float* __restrict__ b1,
                const float* __restrict__ gam, const float* __restrict__ bet,
                const float* __restrict__ b2,
                const float* __restrict__ wh, const float* __restrict__ bh,
                float* __restrict__ out)
{
    __shared__ __align__(16) unsigned zxb[PLDW];
    __shared__ __align__(16) unsigned hbb[PLDW];
    __shared__ float red[48];

    const int n    = blockIdx.x;
    const int tid  = threadIdx.x;
    const int lane = tid & 63;
    const int wid  = tid >> 6;          // 0..3: wave owns output rows wid*8..+7
    const int nidx = lane & 31;         // MFMA column
    const int ax   = nidx & 7;          // anchor-of-4px within row
    const int ry   = nidx >> 3;         // row within N-group
    const int hi   = lane >> 5;         // k-half / oc-half selector

    for (int p = tid; p < PLDW; p += 256) { zxb[p] = 0u; hbb[p] = 0u; }
    __syncthreads();

    {   // image -> bundle ch 5..7 (each thread one 1x4 strip)
        const int yy = tid >> 3, xx0 = (tid & 7) << 2;
        float4 i0 = *(const float4*)&image[(n * 3 + 0) * 1024 + yy * 32 + xx0];
        float4 i1 = *(const float4*)&image[(n * 3 + 1) * 1024 + yy * 32 + xx0];
        float4 i2 = *(const float4*)&image[(n * 3 + 2) * 1024 + yy * 32 + xx0];
        float a0[4] = {i0.x, i0.y, i0.z, i0.w};
        float a1[4] = {i1.x, i1.y, i1.z, i1.w};
        float a2[4] = {i2.x, i2.y, i2.z, i2.w};
        #pragma unroll
        for (int i = 0; i < 4; ++i) {
            unsigned* bp = (unsigned*)((char*)zxb + bofs(yy + 2, xx0 + 2 + i));
            bp[2] = pk2(0.f, a0[i]);
            bp[3] = pk2(a1[i], a2[i]);
        }
    }

    // weight A-fragments in registers (80 + 60 = 140 VGPR)
    uint4 cw1[20];
    uint2 cw2a[20];
    unsigned cw2b[20];
    #pragma unroll
    for (int c = 0; c < 20; ++c) {
        cw1[c]  = *(const uint4*)&wks[(c * 64 + lane) * 4];
        cw2a[c] = *(const uint2*)&wks[5120 + (c * 64 + lane) * 2];
        cw2b[c] = wks[7680 + c * 64 + lane];
    }
    // swizzled x-offsets: chunk c reads x = 4ax + hi + 2(c&3), ty = c>>2
    int sx[4];
    #pragma unroll
    for (int i = 0; i < 4; ++i) sx[i] = swzx(4 * ax + hi + 2 * i);

    float b1q[4], b2q[4];
    #pragma unroll
    for (int j = 0; j < 4; ++j) {
        int oc = 4 * hi + j;
        b1q[j] = (oc < 6) ? b1[oc] : 0.f;
        b2q[j] = (oc < 5) ? b2[oc] : 0.f;
    }

    __syncthreads();

    const char* zb = (const char*)zxb;
    const char* hb = (const char*)hbb;
    const int base0 = (wid * 8 + ry) * ROWB;      // N-group 0 plane-row base
    const int base1 = base0 + 4 * ROWB;           // N-group 1

    #pragma unroll 1
    for (int it = 0; it < 30; ++it) {
        // ================= conv1 (20 chunks x 2 N-groups) =================
        f32x16 acc[2];
        #pragma unroll
        for (int g = 0; g < 2; ++g)
            #pragma unroll
            for (int r = 0; r < 16; ++r) acc[g][r] = b1q[r & 3];
        #pragma unroll
        for (int c = 0; c < 20; ++c) {
            half8 wf = __builtin_bit_cast(half8, cw1[c]);
            const int off = (c >> 2) * ROWB + sx[c & 3];
            half8 p0 = *(const half8*)(zb + base0 + off);
            acc[0] = __builtin_amdgcn_mfma_f32_32x32x16_f16(wf, p0, acc[0], 0, 0, 0);
            half8 p1 = *(const half8*)(zb + base1 + off);
            acc[1] = __builtin_amdgcn_mfma_f32_32x32x16_f16(wf, p1, acc[1], 0, 0, 0);
        }

        // ---- leaky (kept in regs) + GN partial stats ----
        float ps_a = 0.f, pq_a = 0.f, ps_b = 0.f, pq_b = 0.f;
        #pragma unroll
        for (int g = 0; g < 2; ++g)
            #pragma unroll
            for (int r = 0; r < 16; ++r) {
                float v = lrelu(acc[g][r]);
                acc[g][r] = v;
                if ((r & 3) < 2) { ps_a += v; pq_a = fmaf(v, v, pq_a); }
                else             { ps_b += v; pq_b = fmaf(v, v, pq_b); }
            }
        // hi=0: (a,b) = (group0, group1); hi=1: a = group2 (b = oc6/7 zeros)
        #pragma unroll
        for (int m = 1; m <= 16; m <<= 1) {
            ps_a += __shfl_xor(ps_a, m); pq_a += __shfl_xor(pq_a, m);
            ps_b += __shfl_xor(ps_b, m); pq_b += __shfl_xor(pq_b, m);
        }
        if (lane == 0)  { red[wid * 8 + 0] = ps_a; red[wid * 8 + 1] = ps_b;
                          red[wid * 8 + 4] = pq_a; red[wid * 8 + 5] = pq_b; }
        if (lane == 32) { red[wid * 8 + 2] = ps_a; red[wid * 8 + 6] = pq_a; }
        __syncthreads();                               // B1

        // ---- GN fold (every thread; broadcast reads) ----
        float scv[8], shv[8];
        #pragma unroll
        for (int g3 = 0; g3 < 3; ++g3) {
            float s = 0.f, q = 0.f;
            #pragma unroll
            for (int w = 0; w < 4; ++w) { s += red[w * 8 + g3]; q += red[w * 8 + 4 + g3]; }
            float mean = s * (1.f / 2048.f);
            float var  = q * (1.f / 2048.f) - mean * mean;
            float inv  = rsqrtf(var + 1e-5f);
            #pragma unroll
            for (int k = 0; k < 2; ++k) {
                int c = 2 * g3 + k;
                scv[c] = inv * gam[c];
                shv[c] = bet[c] - mean * scv[c];
            }
        }
        scv[6] = scv[7] = shv[6] = shv[7] = 0.f;

        // ---- write normalized h (zero pads stay exact) ----
        #pragma unroll
        for (int g = 0; g < 2; ++g) {
            const int yrow = wid * 8 + g * 4 + ry + 2;
            #pragma unroll
            for (int d = 0; d < 4; ++d) {
                float h0 = fmaf(acc[g][4 * d + 0], scv[4 * hi + 0], shv[4 * hi + 0]);
                float h1 = fmaf(acc[g][4 * d + 1], scv[4 * hi + 1], shv[4 * hi + 1]);
                float h2 = fmaf(acc[g][4 * d + 2], scv[4 * hi + 2], shv[4 * hi + 2]);
                float h3 = fmaf(acc[g][4 * d + 3], scv[4 * hi + 3], shv[4 * hi + 3]);
                char* wp = (char*)hbb + bofs(yrow, 4 * ax + d + 2) + hi * 8;
                *(uint2*)wp = make_uint2(pk2(h0, h1), pk2(h2, h3));
            }
        }
        __syncthreads();                               // B2

        // ================= conv2 (plain weights, plain bias) =================
        #pragma unroll
        for (int g = 0; g < 2; ++g)
            #pragma unroll
            for (int r = 0; r < 16; ++r) acc[g][r] = b2q[r & 3];
        #pragma unroll
        for (int c = 0; c < 20; ++c) {
            uint4 w4 = make_uint4(cw2a[c].x, cw2a[c].y, cw2b[c], 0u);
            half8 wf = __builtin_bit_cast(half8, w4);
            const int off = (c >> 2) * ROWB + sx[c & 3];
            half8 p0 = *(const half8*)(hb + base0 + off);
            acc[0] = __builtin_amdgcn_mfma_f32_32x32x16_f16(wf, p0, acc[0], 0, 0, 0);
            half8 p1 = *(const half8*)(hb + base1 + off);
            acc[1] = __builtin_amdgcn_mfma_f32_32x32x16_f16(wf, p1, acc[1], 0, 0, 0);
        }

        // ---- leaky + damped z RMW ----
        #pragma unroll
        for (int g = 0; g < 2; ++g) {
            const int yrow = wid * 8 + g * 4 + ry + 2;
            #pragma unroll
            for (int d = 0; d < 4; ++d) {
                char* zp = (char*)zxb + bofs(yrow, 4 * ax + d + 2);
                if (hi == 0) {        // oc 0..3 = z0..z3: b64 RMW
                    uint2 zo = *(uint2*)zp;
                    float2 za = up2(zo.x), zc = up2(zo.y);
                    float z0 = 0.5f * za.x + 0.5f * lrelu(acc[g][4 * d + 0]);
                    float z1 = 0.5f * za.y + 0.5f * lrelu(acc[g][4 * d + 1]);
                    float z2 = 0.5f * zc.x + 0.5f * lrelu(acc[g][4 * d + 2]);
                    float z3 = 0.5f * zc.y + 0.5f * lrelu(acc[g][4 * d + 3]);
                    *(uint2*)zp = make_uint2(pk2(z0, z1), pk2(z2, z3));
                } else {              // oc4 = z4: u16 RMW (img0 in hi half untouched)
                    _Float16* pz = (_Float16*)(zp + 8);
                    float z4 = 0.5f * (float)pz[0] + 0.5f * lrelu(acc[g][4 * d + 0]);
                    pz[0] = (_Float16)z4;
                }
            }
        }
        __syncthreads();                               // B3
    }

    // ================= head: out[o] = <z, wh[o]> + bh[o] =================
    {
        const int yy = tid >> 3, xx0 = (tid & 7) << 2;
        float zf[5][4];
        #pragma unroll
        for (int i = 0; i < 4; ++i) {
            const unsigned* bp = (const unsigned*)((const char*)zxb + bofs(yy + 2, xx0 + 2 + i));
            float2 f0 = up2(bp[0]), f1 = up2(bp[1]), f2 = up2(bp[2]);
            zf[0][i] = f0.x; zf[1][i] = f0.y; zf[2][i] = f1.x; zf[3][i] = f1.y; zf[4][i] = f2.x;
        }
        float ho[10];
        #pragma unroll
        for (int o = 0; o < 10; ++o) ho[o] = 0.f;
        #pragma unroll
        for (int c = 0; c < 5; ++c) {
            #pragma unroll
            for (int o = 0; o < 10; ++o) {
                float4 wv = *(const float4*)&wh[(o * 5 + c) * 1024 + yy * 32 + xx0];
                ho[o] = fmaf(zf[c][0], wv.x, ho[o]);
                ho[o] = fmaf(zf[c][1], wv.y, ho[o]);
                ho[o] = fmaf(zf[c][2], wv.z, ho[o]);
                ho[o] = fmaf(zf[c][3], wv.w, ho[o]);
            }
        }
        #pragma unroll
        for (int m = 1; m < 64; m <<= 1) {
            #pragma unroll
            for (int o = 0; o < 10; ++o) ho[o] += __shfl_xor(ho[o], m);
        }
        if (lane == 0) {
            #pragma unroll
            for (int o = 0; o < 10; ++o) red[wid * 10 + o] = ho[o];
        }
    }
    __syncthreads();
    if (tid < 10)
        out[n * 10 + tid] = red[tid] + red[10 + tid] + red[20 + tid] + red[30 + tid] + bh[tid];
}

extern "C" void kernel_launch(void* const* d_in, const int* in_sizes, int n_in,
                              void* d_out, int out_size, void* d_ws, size_t ws_size,
                              hipStream_t stream) {
    const float* image = (const float*)d_in[0];
    const float* w1    = (const float*)d_in[1];
    const float* b1    = (const float*)d_in[2];
    const float* gam   = (const float*)d_in[3];
    const float* bet   = (const float*)d_in[4];
    const float* w2    = (const float*)d_in[5];
    const float* b2    = (const float*)d_in[6];
    const float* wh    = (const float*)d_in[7];
    const float* bh    = (const float*)d_in[8];
    float* out = (float*)d_out;
    unsigned* ws = (unsigned*)d_ws;

    pack_weights<<<10, 256, 0, stream>>>(w1, w2, ws);

    const int N = in_sizes[0] / (3 * 32 * 32);   // 1024 images
    deq_kernel<<<N, 256, 0, stream>>>(image, ws, b1, gam, bet, b2, wh, bh, out);
}

// Round 13
// 379.861 us; speedup vs baseline: 1.5560x; 1.5560x over previous
//
#include <hip/hip_runtime.h>
#include <hip/hip_fp16.h>

// DEQ classifier, dx-packed 16x16x32 MFMA (R9 structure), 4-blocks/CU fit.
// One block per image (1024 x 256 threads, 4 waves; wave owns 8 y-rows as
// two 4-row passes). LDS: ONE combined buffer of 70 rows x 36 bundles
// (8-ch f16 pixel bundles, 16 B), swizzle bofs(r,x)=((r*36+x)*16)^((x&8)<<1)
// (bijective: 36r even, xor only swaps x<->x^1 within x&8 blocks).
//   rows 0..35  : zx plane (interior rows 2..33; ch z0..z4, img0..2)
//   rows 34..69 : h  plane (interior rows 36..67; ch h0..h5, 0, 0)
//   rows 34,35 SHARED (zx bottom pad == h top pad) -- both always ZERO.
// Total 40320 B + red 192 B -> 40960 alloc -> EXACTLY 4 blocks/CU (160 KB).
// Conv as MFMA 16x16x32 (proven R9 mapping):
//   A[16 rows=(dx*8+oc)][32 k] : weight frags in VGPRs (cw1/cw2, 64 regs)
//   B[32 k][16 cols=anchor a]  : pixel bundle at (ay+ty, 2a+tx), 1 b128/lane
//   k = (tap = ty*6+tx over 5x6 window, ch); 8 chunks of 4 taps.
//   D: col=lane&15=anchor, row=(lane>>4)*4+reg = dx*8+oc
// GroupNorm: h written unnormalized pre-B1; after fold each thread RMWs its
// OWN h bundles with += sh/sc (shift-into-values); conv2 weights scaled by
// sc (hmul2 per chunk), bias plain b2. Zero pads exact (sc*(a1+sh/sc)=h_norm
// interior, 0 at pads). No pad-rewrite, no S2 table.
// Register budget: launch_bounds(256,2) -> cap 128 (rule: 256/min_waves_eu);
// ~120 used. Tripwire: FETCH_SIZE ~7 MB; spill shows as FETCH/WRITE blowup.

typedef _Float16 half8 __attribute__((ext_vector_type(8)));
typedef float f32x4 __attribute__((ext_vector_type(4)));

#define NROWS 70
#define HOFF  34                  // h-plane row offset in combined buffer

__device__ __forceinline__ unsigned pk2(float a, float b) {
    __half2 h = __float22half2_rn(make_float2(a, b));
    return *reinterpret_cast<unsigned*>(&h);
}
__device__ __forceinline__ float2 up2(unsigned u) {
    __half2 h = *reinterpret_cast<__half2*>(&u);
    return __half22float2(h);
}
__device__ __forceinline__ unsigned hmul2(unsigned a, unsigned b) {
    __half2 r = __hmul2(*reinterpret_cast<__half2*>(&a), *reinterpret_cast<__half2*>(&b));
    return *reinterpret_cast<unsigned*>(&r);
}
__device__ __forceinline__ float lrelu(float x) { return fmaxf(x, 0.01f * x); }
__device__ __forceinline__ int bofs(int r, int x) {
    return ((r * 36 + x) * 16) ^ ((x & 8) << 1);
}

// ---- prep: dx-packed A-fragments (identical to R9, minus S2 table) ----
// ws[0..2047]    : conv1 A-frags, 8 chunks x 64 lanes x 4 dw
//   lane l: row = l&15 (dx=row>>3, oc=row&7), tap = 4c + (l>>4); elem j = ch j
//   value = w1[oc][ch][ty][tx-dx] (ty=tap/6, tx=tap%6), 0 if OOB/oc>=6/tap>=30
// ws[2048..4095] : conv2 A-frags from w2 (0 if oc>=5, ch>=6)
__global__ void pack_weights(const float* __restrict__ w1,
                             const float* __restrict__ w2,
                             unsigned* __restrict__ ws)
{
    int t = blockIdx.x * 256 + threadIdx.x;
    if (t < 512) {
        int c = t >> 6, l = t & 63;
        int row = l & 15, tgw = l >> 4;
        int dx = row >> 3, oc = row & 7, tap = 4 * c + tgw;
        unsigned q[4];
        #pragma unroll
        for (int d = 0; d < 4; ++d) {
            float v0 = 0.f, v1 = 0.f;
            if (oc < 6 && tap < 30) {
                int ty = tap / 6, kx = tap % 6 - dx;
                if (kx >= 0 && kx < 5) {
                    v0 = w1[(oc * 8 + 2 * d) * 25 + ty * 5 + kx];
                    v1 = w1[(oc * 8 + 2 * d + 1) * 25 + ty * 5 + kx];
                }
            }
            q[d] = pk2(v0, v1);
        }
        *(uint4*)&ws[t * 4] = make_uint4(q[0], q[1], q[2], q[3]);
    } else if (t < 1024) {
        int u = t - 512;
        int c = u >> 6, l = u & 63;
        int row = l & 15, tgw = l >> 4;
        int dx = row >> 3, oc = row & 7, tap = 4 * c + tgw;
        unsigned q[4];
        #pragma unroll
        for (int d = 0; d < 4; ++d) {
            float v0 = 0.f, v1 = 0.f;
            if (oc < 5 && tap < 30) {
                int ty = tap / 6, kx = tap % 6 - dx;
                if (kx >= 0 && kx < 5) {
                    if (2 * d < 6)     v0 = w2[(oc * 6 + 2 * d) * 25 + ty * 5 + kx];
                    if (2 * d + 1 < 6) v1 = w2[(oc * 6 + 2 * d + 1) * 25 + ty * 5 + kx];
                }
            }
            q[d] = pk2(v0, v1);
        }
        *(uint4*)&ws[2048 + u * 4] = make_uint4(q[0], q[1], q[2], q[3]);
    }
}

__global__ __launch_bounds__(256, 2)
void deq_kernel(const float* __restrict__ image,
                const unsigned* __restrict__ wks,
                const float* __restrict__ b1,
                const float* __restrict__ gam, const float* __restrict__ bet,
                const float* __restrict__ b2,
                const float* __restrict__ wh, const float* __restrict__ bh,
                float* __restrict__ out)
{
    __shared__ __align__(16) unsigned buf[NROWS * 36 * 4];   // 40320 B
    __shared__ float red[48];

    const int n    = blockIdx.x;
    const int tid  = threadIdx.x;
    const int lane = tid & 63;
    const int wid  = tid >> 6;          // 0..3: wave owns output rows wid*8..+7
    const int col  = lane & 15;         // anchor: pixels 2col, 2col+1
    const int tg   = lane >> 4;
    const int dxl  = tg >> 1;           // this lane's output dx
    const int sub  = tg & 1;            // 0: ch0-3, 1: ch4-7

    for (int p = tid; p < NROWS * 36 * 4; p += 256) buf[p] = 0u;
    __syncthreads();

    {   // image -> zx bundle ch 5..7 (each thread one 1x4 strip)
        const int yy = tid >> 3, xx0 = (tid & 7) << 2;
        float4 i0 = *(const float4*)&image[(n * 3 + 0) * 1024 + yy * 32 + xx0];
        float4 i1 = *(const float4*)&image[(n * 3 + 1) * 1024 + yy * 32 + xx0];
        float4 i2 = *(const float4*)&image[(n * 3 + 2) * 1024 + yy * 32 + xx0];
        float a0[4] = {i0.x, i0.y, i0.z, i0.w};
        float a1[4] = {i1.x, i1.y, i1.z, i1.w};
        float a2[4] = {i2.x, i2.y, i2.z, i2.w};
        #pragma unroll
        for (int i = 0; i < 4; ++i) {
            unsigned* bp = (unsigned*)((char*)buf + bofs(yy + 2, xx0 + 2 + i));
            bp[2] = pk2(0.f, a0[i]);
            bp[3] = pk2(a1[i], a2[i]);
        }
    }

    // weight A-fragments in registers (64 VGPR, reused all 30 iters)
    uint4 cw1[8], cw2[8];
    #pragma unroll
    for (int c = 0; c < 8; ++c) {
        cw1[c] = *(const uint4*)&wks[(c * 64 + lane) * 4];
        cw2[c] = *(const uint4*)&wks[2048 + (c * 64 + lane) * 4];
    }
    // per-lane per-chunk B-read byte offsets
    int toff[8];
    #pragma unroll
    for (int c = 0; c < 8; ++c) {
        int t = 4 * c + tg;
        int ty = 0, tx = 0;
        if (t < 30) { ty = t / 6; tx = t % 6; }
        int xr = 2 * col + tx;
        toff[c] = ty * 576 + ((xr * 16) ^ ((xr & 8) << 1));
    }

    float b1q[4], b2q[4];
    #pragma unroll
    for (int r = 0; r < 4; ++r) {
        int oc = (tg * 4 + r) & 7;
        b1q[r] = (oc < 6) ? b1[oc] : 0.f;
        b2q[r] = (oc < 5) ? b2[oc] : 0.f;
    }
    const f32x4 ai1 = {b1q[0], b1q[1], b1q[2], b1q[3]};
    const f32x4 ai2 = {b2q[0], b2q[1], b2q[2], b2q[3]};

    __syncthreads();

    const char* zb = (const char*)buf;
    const int ay0 = wid << 3;           // wave owns rows ay0..ay0+7
    const int hwp0 = bofs(0, 2 * col + dxl + 2) + sub * 8;  // h-write x-part

    #pragma unroll 1
    for (int it = 0; it < 30; ++it) {
        // ========== conv1 (two 4-row passes, chunk-outer; unnorm h out) ==========
        float ps_lo = 0.f, ps_hi = 0.f, pq_lo = 0.f, pq_hi = 0.f;
        #pragma unroll
        for (int half = 0; half < 2; ++half) {
            const int ayh = ay0 + half * 4;
            f32x4 acc[4];
            #pragma unroll
            for (int g = 0; g < 4; ++g) acc[g] = ai1;
            #pragma unroll
            for (int c = 0; c < 8; ++c) {
                half8 wf = __builtin_bit_cast(half8, cw1[c]);
                #pragma unroll
                for (int g = 0; g < 4; ++g) {
                    half8 pv = *(const half8*)(zb + (ayh + g) * 576 + toff[c]);
                    acc[g] = __builtin_amdgcn_mfma_f32_16x16x32_f16(wf, pv, acc[g], 0, 0, 0);
                }
            }
            #pragma unroll
            for (int g = 0; g < 4; ++g) {
                float h0 = lrelu(acc[g][0]), h1 = lrelu(acc[g][1]);
                float h2 = lrelu(acc[g][2]), h3 = lrelu(acc[g][3]);
                ps_lo += h0 + h1;  pq_lo = fmaf(h0, h0, fmaf(h1, h1, pq_lo));
                ps_hi += h2 + h3;  pq_hi = fmaf(h2, h2, fmaf(h3, h3, pq_hi));
                char* wp = (char*)buf + (ayh + g + 2 + HOFF) * 576 + hwp0;
                *(uint2*)wp = make_uint2(pk2(h0, h1), pk2(h2, h3));
            }
        }

        // GN stats reduce: anchors (xor 1..8) then dx halves (xor 32)
        #pragma unroll
        for (int m = 1; m <= 8; m <<= 1) {
            ps_lo += __shfl_xor(ps_lo, m); ps_hi += __shfl_xor(ps_hi, m);
            pq_lo += __shfl_xor(pq_lo, m); pq_hi += __shfl_xor(pq_hi, m);
        }
        ps_lo += __shfl_xor(ps_lo, 32); ps_hi += __shfl_xor(ps_hi, 32);
        pq_lo += __shfl_xor(pq_lo, 32); pq_hi += __shfl_xor(pq_hi, 32);
        if (lane == 0)  { red[wid * 8 + 0] = ps_lo; red[wid * 8 + 1] = ps_hi;
                          red[wid * 8 + 4] = pq_lo; red[wid * 8 + 5] = pq_hi; }
        if (lane == 16) { red[wid * 8 + 2] = ps_lo; red[wid * 8 + 6] = pq_lo; }
        __syncthreads();                               // B1

        // ---- GN fold: scales for conv2 weights, shifts into h values ----
        float scv[6], shv[6];
        #pragma unroll
        for (int g3 = 0; g3 < 3; ++g3) {
            float s = 0.f, q = 0.f;
            #pragma unroll
            for (int w = 0; w < 4; ++w) { s += red[w * 8 + g3]; q += red[w * 8 + 4 + g3]; }
            float mean = s * (1.f / 2048.f);
            float var  = q * (1.f / 2048.f) - mean * mean;
            float inv  = rsqrtf(var + 1e-5f);
            #pragma unroll
            for (int k = 0; k < 2; ++k) {
                int c = 2 * g3 + k;
                scv[c] = inv * gam[c];
                shv[c] = bet[c] - mean * scv[c];
            }
        }
        unsigned sp0 = pk2(scv[0], scv[1]), sp1 = pk2(scv[2], scv[3]), sp2 = pk2(scv[4], scv[5]);
        // this thread's 4 channels' shift sh/sc (0 for oc>=6)
        float shq[4];
        #pragma unroll
        for (int r = 0; r < 4; ++r) {
            int ocr = (tg * 4 + r) & 7;
            shq[r] = (ocr < 6 && fabsf(scv[ocr]) > 1e-20f) ? shv[ocr] / scv[ocr] : 0.f;
        }
        // RMW own h bundles: v += sh/sc  (8 rows x uint2, disjoint per thread)
        #pragma unroll
        for (int g8 = 0; g8 < 8; ++g8) {
            char* wp = (char*)buf + (ay0 + g8 + 2 + HOFF) * 576 + hwp0;
            uint2 v = *(uint2*)wp;
            float2 va = up2(v.x), vb = up2(v.y);
            *(uint2*)wp = make_uint2(pk2(va.x + shq[0], va.y + shq[1]),
                                     pk2(vb.x + shq[2], vb.y + shq[3]));
        }
        __syncthreads();                               // B2

        // ====== conv2 (two 4-row passes; w2*sc inline per chunk, bias b2) ======
        #pragma unroll
        for (int half = 0; half < 2; ++half) {
            const int ayh = ay0 + half * 4;
            f32x4 acc[4];
            #pragma unroll
            for (int g = 0; g < 4; ++g) acc[g] = ai2;
            #pragma unroll
            for (int c = 0; c < 8; ++c) {
                uint4 wsc;
                wsc.x = hmul2(cw2[c].x, sp0);
                wsc.y = hmul2(cw2[c].y, sp1);
                wsc.z = hmul2(cw2[c].z, sp2);
                wsc.w = 0u;
                half8 wf = __builtin_bit_cast(half8, wsc);
                #pragma unroll
                for (int g = 0; g < 4; ++g) {
                    half8 pv = *(const half8*)(zb + (ayh + g + HOFF) * 576 + toff[c]);
                    acc[g] = __builtin_amdgcn_mfma_f32_16x16x32_f16(wf, pv, acc[g], 0, 0, 0);
                }
            }
            #pragma unroll
            for (int g = 0; g < 4; ++g) {
                char* zp = (char*)buf + bofs(ayh + g + 2, 2 * col + dxl + 2);
                if (sub == 0) {       // z0..z3: b64 RMW
                    uint2 zo = *(uint2*)zp;
                    float2 za = up2(zo.x), zc = up2(zo.y);
                    float z0 = 0.5f * za.x + 0.5f * lrelu(acc[g][0]);
                    float z1 = 0.5f * za.y + 0.5f * lrelu(acc[g][1]);
                    float z2 = 0.5f * zc.x + 0.5f * lrelu(acc[g][2]);
                    float z3 = 0.5f * zc.y + 0.5f * lrelu(acc[g][3]);
                    *(uint2*)zp = make_uint2(pk2(z0, z1), pk2(z2, z3));
                } else {              // z4: u16 RMW (img0 in hi half untouched)
                    _Float16* pz = (_Float16*)(zp + 8);
                    float z4 = 0.5f * (float)pz[0] + 0.5f * lrelu(acc[g][0]);
                    pz[0] = (_Float16)z4;
                }
            }
        }
        __syncthreads();                               // B3
    }

    // ================= head: out[o] = <z, wh[o]> + bh[o] =================
    {
        const int yy = tid >> 3, xx0 = (tid & 7) << 2;
        float zf[5][4];
        #pragma unroll
        for (int i = 0; i < 4; ++i) {
            const unsigned* bp = (const unsigned*)((const char*)buf + bofs(yy + 2, xx0 + 2 + i));
            float2 f0 = up2(bp[0]), f1 = up2(bp[1]), f2 = up2(bp[2]);
            zf[0][i] = f0.x; zf[1][i] = f0.y; zf[2][i] = f1.x; zf[3][i] = f1.y; zf[4][i] = f2.x;
        }
        float ho[10];
        #pragma unroll
        for (int o = 0; o < 10; ++o) ho[o] = 0.f;
        #pragma unroll
        for (int c = 0; c < 5; ++c) {
            #pragma unroll
            for (int o = 0; o < 10; ++o) {
                float4 wv = *(const float4*)&wh[(o * 5 + c) * 1024 + yy * 32 + xx0];
                ho[o] = fmaf(zf[c][0], wv.x, ho[o]);
                ho[o] = fmaf(zf[c][1], wv.y, ho[o]);
                ho[o] = fmaf(zf[c][2], wv.z, ho[o]);
                ho[o] = fmaf(zf[c][3], wv.w, ho[o]);
            }
        }
        #pragma unroll
        for (int m = 1; m < 64; m <<= 1) {
            #pragma unroll
            for (int o = 0; o < 10; ++o) ho[o] += __shfl_xor(ho[o], m);
        }
        if (lane == 0) {
            #pragma unroll
            for (int o = 0; o < 10; ++o) red[wid * 10 + o] = ho[o];
        }
    }
    __syncthreads();
    if (tid < 10)
        out[n * 10 + tid] = red[tid] + red[10 + tid] + red[20 + tid] + red[30 + tid] + bh[tid];
}

extern "C" void kernel_launch(void* const* d_in, const int* in_sizes, int n_in,
                              void* d_out, int out_size, void* d_ws, size_t ws_size,
                              hipStream_t stream) {
    const float* image = (const float*)d_in[0];
    const float* w1    = (const float*)d_in[1];
    const float* b1    = (const float*)d_in[2];
    const float* gam   = (const float*)d_in[3];
    const float* bet   = (const float*)d_in[4];
    const float* w2    = (const float*)d_in[5];
    const float* b2    = (const float*)d_in[6];
    const float* wh    = (const float*)d_in[7];
    const float* bh    = (const float*)d_in[8];
    float* out = (float*)d_out;
    unsigned* ws = (unsigned*)d_ws;

    pack_weights<<<4, 256, 0, stream>>>(w1, w2, ws);

    const int N = in_sizes[0] / (3 * 32 * 32);   // 1024 images
    deq_kernel<<<N, 256, 0, stream>>>(image, ws, b1, gam, bet, b2, wh, bh, out);
}

// Round 14
// 376.704 us; speedup vs baseline: 1.5691x; 1.0084x over previous
//
#include <hip/hip_runtime.h>
#include <hip/hip_fp16.h>

// DEQ classifier, dx-packed 16x16x32 MFMA (R9 best-known structure), with
// conv2 weight fragments in LDS to cut per-wave register footprint.
// One block per image (1024 x 256 threads, 4 waves; wave owns 8 y-rows as
// two 4-row passes). LDS: two planes of 8-ch f16 pixel bundles (16 B) on a
// 36x36 zero-padded grid, swizzle bofs(y,x)=((y*36+x)*16)^((x&8)<<1), plus
// conv2 A-frag table (8 KB).
//   zxb: [z0..z4, img0..2]    hbb: [h0..h5, 0, 0]
// Conv as MFMA 16x16x32:
//   A[16 rows=(dx*8+oc)][32 k] : conv1 frags in VGPRs (32 regs); conv2 frags
//                                read per chunk from LDS (contig 1KB/wave,
//                                conflict-free)
//   B[32 k][16 cols=anchor a]  : pixel bundle at (ay+ty, 2a+tx), 1 b128/lane
//   k = (tap = ty*6+tx over 5x6 window, ch); 8 chunks of 4 taps.
//   D: col=lane&15=anchor, row=(lane>>4)*4+reg = dx*8+oc
// GroupNorm folded into conv2 (w2*sc inline per chunk, h-pads=-sh/sc,
// bias2' = b2 + S2*sh) -- R9's proven scheme (R13's shift-RMW was slower).
// Register budget: launch_bounds(256,2) cap 128 arch; dropping cw2 (-32)
// targets arch+acc <= ~120 total -> more waves/SIMD (occupancy experiment).
// Tripwire: FETCH_SIZE ~7 MB; spill shows as FETCH/WRITE blowup.

typedef _Float16 half8 __attribute__((ext_vector_type(8)));
typedef float f32x4 __attribute__((ext_vector_type(4)));

__device__ __forceinline__ unsigned pk2(float a, float b) {
    __half2 h = __float22half2_rn(make_float2(a, b));
    return *reinterpret_cast<unsigned*>(&h);
}
__device__ __forceinline__ float2 up2(unsigned u) {
    __half2 h = *reinterpret_cast<__half2*>(&u);
    return __half22float2(h);
}
__device__ __forceinline__ unsigned hmul2(unsigned a, unsigned b) {
    __half2 r = __hmul2(*reinterpret_cast<__half2*>(&a), *reinterpret_cast<__half2*>(&b));
    return *reinterpret_cast<unsigned*>(&r);
}
__device__ __forceinline__ float lrelu(float x) { return fmaxf(x, 0.01f * x); }
__device__ __forceinline__ int bofs(int y, int x) {
    return ((y * 36 + x) * 16) ^ ((x & 8) << 1);
}

// ---- prep: dx-packed A-fragments + tap-sum table (identical to R9) ----
// ws[0..2047]    : conv1 A-frags, 8 chunks x 64 lanes x 4 dw
//   lane l: row = l&15 (dx=row>>3, oc=row&7), tap = 4c + (l>>4); elem j = ch j
//   value = w1[oc][ch][ty][tx-dx] (ty=tap/6, tx=tap%6), 0 if OOB/oc>=6/tap>=30
// ws[2048..4095] : conv2 A-frags from w2 (0 if oc>=5, ch>=6)
// ws[4096..4125] : S2[oc][ch] = sum_tap w2[oc][ch][tap]  (f32)
__global__ void pack_weights(const float* __restrict__ w1,
                             const float* __restrict__ w2,
                             unsigned* __restrict__ ws)
{
    int t = blockIdx.x * 256 + threadIdx.x;
    if (t < 512) {
        int c = t >> 6, l = t & 63;
        int row = l & 15, tgw = l >> 4;
        int dx = row >> 3, oc = row & 7, tap = 4 * c + tgw;
        unsigned q[4];
        #pragma unroll
        for (int d = 0; d < 4; ++d) {
            float v0 = 0.f, v1 = 0.f;
            if (oc < 6 && tap < 30) {
                int ty = tap / 6, kx = tap % 6 - dx;
                if (kx >= 0 && kx < 5) {
                    v0 = w1[(oc * 8 + 2 * d) * 25 + ty * 5 + kx];
                    v1 = w1[(oc * 8 + 2 * d + 1) * 25 + ty * 5 + kx];
                }
            }
            q[d] = pk2(v0, v1);
        }
        *(uint4*)&ws[t * 4] = make_uint4(q[0], q[1], q[2], q[3]);
    } else if (t < 1024) {
        int u = t - 512;
        int c = u >> 6, l = u & 63;
        int row = l & 15, tgw = l >> 4;
        int dx = row >> 3, oc = row & 7, tap = 4 * c + tgw;
        unsigned q[4];
        #pragma unroll
        for (int d = 0; d < 4; ++d) {
            float v0 = 0.f, v1 = 0.f;
            if (oc < 5 && tap < 30) {
                int ty = tap / 6, kx = tap % 6 - dx;
                if (kx >= 0 && kx < 5) {
                    if (2 * d < 6)     v0 = w2[(oc * 6 + 2 * d) * 25 + ty * 5 + kx];
                    if (2 * d + 1 < 6) v1 = w2[(oc * 6 + 2 * d + 1) * 25 + ty * 5 + kx];
                }
            }
            q[d] = pk2(v0, v1);
        }
        *(uint4*)&ws[2048 + u * 4] = make_uint4(q[0], q[1], q[2], q[3]);
    } else if (t < 1054) {
        int idx = t - 1024;
        int oc = idx / 6, ch = idx % 6;
        float s = 0.f;
        for (int tap = 0; tap < 25; ++tap) s += w2[(oc * 6 + ch) * 25 + tap];
        ((float*)ws)[4096 + idx] = s;
    }
}

__global__ __launch_bounds__(256, 2)
void deq_kernel(const float* __restrict__ image,
                const unsigned* __restrict__ wks,
                const float* __restrict__ b1,
                const float* __restrict__ gam, const float* __restrict__ bet,
                const float* __restrict__ b2,
                const float* __restrict__ wh, const float* __restrict__ bh,
                float* __restrict__ out)
{
    __shared__ __align__(16) unsigned zxb[36 * 36 * 4];
    __shared__ __align__(16) unsigned hbb[36 * 36 * 4];
    __shared__ __align__(16) unsigned wl2[2048];   // conv2 A-frags (8 KB)
    __shared__ float red[48];
    __shared__ float s2s[32];

    const int n    = blockIdx.x;
    const int tid  = threadIdx.x;
    const int lane = tid & 63;
    const int wid  = tid >> 6;          // 0..3: wave owns output rows wid*8..+7
    const int col  = lane & 15;         // anchor: pixels 2col, 2col+1
    const int tg   = lane >> 4;
    const int dxl  = tg >> 1;           // this lane's output dx
    const int sub  = tg & 1;            // 0: ch0-3, 1: ch4-7

    for (int p = tid; p < 36 * 36 * 4; p += 256) { zxb[p] = 0u; hbb[p] = 0u; }
    for (int p = tid; p < 2048; p += 256) wl2[p] = wks[2048 + p];
    if (tid < 30) s2s[tid] = ((const float*)wks)[4096 + tid];
    __syncthreads();

    {   // image -> bundle ch 5..7 (each thread one 1x4 strip)
        const int yy = tid >> 3, xx0 = (tid & 7) << 2;
        float4 i0 = *(const float4*)&image[(n * 3 + 0) * 1024 + yy * 32 + xx0];
        float4 i1 = *(const float4*)&image[(n * 3 + 1) * 1024 + yy * 32 + xx0];
        float4 i2 = *(const float4*)&image[(n * 3 + 2) * 1024 + yy * 32 + xx0];
        float a0[4] = {i0.x, i0.y, i0.z, i0.w};
        float a1[4] = {i1.x, i1.y, i1.z, i1.w};
        float a2[4] = {i2.x, i2.y, i2.z, i2.w};
        #pragma unroll
        for (int i = 0; i < 4; ++i) {
            unsigned* bp = (unsigned*)((char*)zxb + bofs(yy + 2, xx0 + 2 + i));
            bp[2] = pk2(0.f, a0[i]);
            bp[3] = pk2(a1[i], a2[i]);
        }
    }

    // conv1 weight A-fragments in registers (32 VGPR)
    uint4 cw1[8];
    #pragma unroll
    for (int c = 0; c < 8; ++c)
        cw1[c] = *(const uint4*)&wks[(c * 64 + lane) * 4];

    // per-lane per-chunk B-read byte offsets
    int toff[8];
    #pragma unroll
    for (int c = 0; c < 8; ++c) {
        int t = 4 * c + tg;
        int ty = 0, tx = 0;
        if (t < 30) { ty = t / 6; tx = t % 6; }
        int xr = 2 * col + tx;
        toff[c] = ty * 576 + ((xr * 16) ^ ((xr & 8) << 1));
    }

    float b1q[4], b2q[4];
    #pragma unroll
    for (int r = 0; r < 4; ++r) {
        int oc = (tg * 4 + r) & 7;
        b1q[r] = (oc < 6) ? b1[oc] : 0.f;
        b2q[r] = (oc < 5) ? b2[oc] : 0.f;
    }
    const f32x4 ai1 = {b1q[0], b1q[1], b1q[2], b1q[3]};

    __syncthreads();

    const char* zb = (const char*)zxb;
    const char* hb = (const char*)hbb;
    const int ay0 = wid << 3;           // wave owns rows ay0..ay0+7
    const int wlo = lane << 2;          // this lane's frag dword base in wl2

    #pragma unroll 1
    for (int it = 0; it < 30; ++it) {
        // ================= conv1 (two 4-row passes, chunk-outer) =================
        float ps_lo = 0.f, ps_hi = 0.f, pq_lo = 0.f, pq_hi = 0.f;
        #pragma unroll
        for (int half = 0; half < 2; ++half) {
            const int ayh = ay0 + half * 4;
            f32x4 acc[4];
            #pragma unroll
            for (int g = 0; g < 4; ++g) acc[g] = ai1;
            #pragma unroll
            for (int c = 0; c < 8; ++c) {
                half8 wf = __builtin_bit_cast(half8, cw1[c]);
                #pragma unroll
                for (int g = 0; g < 4; ++g) {
                    half8 pv = *(const half8*)(zb + (ayh + g) * 576 + toff[c]);
                    acc[g] = __builtin_amdgcn_mfma_f32_16x16x32_f16(wf, pv, acc[g], 0, 0, 0);
                }
            }
            #pragma unroll
            for (int g = 0; g < 4; ++g) {
                float h0 = lrelu(acc[g][0]), h1 = lrelu(acc[g][1]);
                float h2 = lrelu(acc[g][2]), h3 = lrelu(acc[g][3]);
                ps_lo += h0 + h1;  pq_lo = fmaf(h0, h0, fmaf(h1, h1, pq_lo));
                ps_hi += h2 + h3;  pq_hi = fmaf(h2, h2, fmaf(h3, h3, pq_hi));
                char* wp = (char*)hbb + bofs(ayh + g + 2, 2 * col + dxl + 2) + sub * 8;
                *(uint2*)wp = make_uint2(pk2(h0, h1), pk2(h2, h3));
            }
        }

        // GN stats reduce: anchors (xor 1..8) then dx halves (xor 32)
        #pragma unroll
        for (int m = 1; m <= 8; m <<= 1) {
            ps_lo += __shfl_xor(ps_lo, m); ps_hi += __shfl_xor(ps_hi, m);
            pq_lo += __shfl_xor(pq_lo, m); pq_hi += __shfl_xor(pq_hi, m);
        }
        ps_lo += __shfl_xor(ps_lo, 32); ps_hi += __shfl_xor(ps_hi, 32);
        pq_lo += __shfl_xor(pq_lo, 32); pq_hi += __shfl_xor(pq_hi, 32);
        if (lane == 0)  { red[wid * 8 + 0] = ps_lo; red[wid * 8 + 1] = ps_hi;
                          red[wid * 8 + 4] = pq_lo; red[wid * 8 + 5] = pq_hi; }
        if (lane == 16) { red[wid * 8 + 2] = ps_lo; red[wid * 8 + 6] = pq_lo; }
        __syncthreads();                               // B1

        // ---- fold GN into conv2 operands ----
        float scv[6], shv[6];
        #pragma unroll
        for (int g3 = 0; g3 < 3; ++g3) {
            float s = 0.f, q = 0.f;
            #pragma unroll
            for (int w = 0; w < 4; ++w) { s += red[w * 8 + g3]; q += red[w * 8 + 4 + g3]; }
            float mean = s * (1.f / 2048.f);
            float var  = q * (1.f / 2048.f) - mean * mean;
            float inv  = rsqrtf(var + 1e-5f);
            #pragma unroll
            for (int k = 0; k < 2; ++k) {
                int c = 2 * g3 + k;
                scv[c] = inv * gam[c];
                shv[c] = bet[c] - mean * scv[c];
            }
        }
        f32x4 ai2;
        #pragma unroll
        for (int r = 0; r < 4; ++r) {
            int ocr = (tg * 4 + r) & 7;
            int base = (ocr < 5) ? ocr * 6 : 0;
            float db = 0.f;
            #pragma unroll
            for (int ch = 0; ch < 6; ++ch) db = fmaf(s2s[base + ch], shv[ch], db);
            ai2[r] = b2q[r] + ((ocr < 5) ? db : 0.f);
        }
        unsigned sp0 = pk2(scv[0], scv[1]), sp1 = pk2(scv[2], scv[3]), sp2 = pk2(scv[4], scv[5]);
        // h pads <- -sh/sc
        {
            float ph[6];
            #pragma unroll
            for (int c = 0; c < 6; ++c) {
                float rs = (fabsf(scv[c]) > 1e-20f) ? 1.f / scv[c] : 0.f;
                ph[c] = -shv[c] * rs;
            }
            uint4 padq = make_uint4(pk2(ph[0], ph[1]), pk2(ph[2], ph[3]), pk2(ph[4], ph[5]), 0u);
            for (int t = tid; t < 272; t += 256) {
                int row, cc;
                if (t < 72)       { row = t / 36;             cc = t % 36; }
                else if (t < 144) { row = 34 + (t - 72) / 36; cc = (t - 72) % 36; }
                else {
                    int q4 = t - 144;
                    row = 2 + (q4 >> 2);
                    int c4 = q4 & 3;
                    cc = (c4 < 2) ? c4 : c4 + 32;
                }
                *(uint4*)((char*)hbb + bofs(row, cc)) = padq;
            }
        }
        __syncthreads();                               // B2

        // ====== conv2 (two 4-row passes; frag from LDS + scale per chunk) ======
        #pragma unroll
        for (int half = 0; half < 2; ++half) {
            const int ayh = ay0 + half * 4;
            f32x4 acc[4];
            #pragma unroll
            for (int g = 0; g < 4; ++g) acc[g] = ai2;
            #pragma unroll
            for (int c = 0; c < 8; ++c) {
                uint4 wr = *(const uint4*)&wl2[c * 256 + wlo];
                uint4 wsc;
                wsc.x = hmul2(wr.x, sp0);
                wsc.y = hmul2(wr.y, sp1);
                wsc.z = hmul2(wr.z, sp2);
                wsc.w = 0u;
                half8 wf = __builtin_bit_cast(half8, wsc);
                #pragma unroll
                for (int g = 0; g < 4; ++g) {
                    half8 pv = *(const half8*)(hb + (ayh + g) * 576 + toff[c]);
                    acc[g] = __builtin_amdgcn_mfma_f32_16x16x32_f16(wf, pv, acc[g], 0, 0, 0);
                }
            }
            #pragma unroll
            for (int g = 0; g < 4; ++g) {
                char* zp = (char*)zxb + bofs(ayh + g + 2, 2 * col + dxl + 2);
                if (sub == 0) {       // z0..z3: b64 RMW
                    uint2 zo = *(uint2*)zp;
                    float2 za = up2(zo.x), zc = up2(zo.y);
                    float z0 = 0.5f * za.x + 0.5f * lrelu(acc[g][0]);
                    float z1 = 0.5f * za.y + 0.5f * lrelu(acc[g][1]);
                    float z2 = 0.5f * zc.x + 0.5f * lrelu(acc[g][2]);
                    float z3 = 0.5f * zc.y + 0.5f * lrelu(acc[g][3]);
                    *(uint2*)zp = make_uint2(pk2(z0, z1), pk2(z2, z3));
                } else {              // z4: u16 RMW (img0 in hi half untouched)
                    _Float16* pz = (_Float16*)(zp + 8);
                    float z4 = 0.5f * (float)pz[0] + 0.5f * lrelu(acc[g][0]);
                    pz[0] = (_Float16)z4;
                }
            }
        }
        __syncthreads();                               // B3
    }

    // ================= head: out[o] = <z, wh[o]> + bh[o] =================
    {
        const int yy = tid >> 3, xx0 = (tid & 7) << 2;
        float zf[5][4];
        #pragma unroll
        for (int i = 0; i < 4; ++i) {
            const unsigned* bp = (const unsigned*)((const char*)zxb + bofs(yy + 2, xx0 + 2 + i));
            float2 f0 = up2(bp[0]), f1 = up2(bp[1]), f2 = up2(bp[2]);
            zf[0][i] = f0.x; zf[1][i] = f0.y; zf[2][i] = f1.x; zf[3][i] = f1.y; zf[4][i] = f2.x;
        }
        float ho[10];
        #pragma unroll
        for (int o = 0; o < 10; ++o) ho[o] = 0.f;
        #pragma unroll
        for (int c = 0; c < 5; ++c) {
            #pragma unroll
            for (int o = 0; o < 10; ++o) {
                float4 wv = *(const float4*)&wh[(o * 5 + c) * 1024 + yy * 32 + xx0];
                ho[o] = fmaf(zf[c][0], wv.x, ho[o]);
                ho[o] = fmaf(zf[c][1], wv.y, ho[o]);
                ho[o] = fmaf(zf[c][2], wv.z, ho[o]);
                ho[o] = fmaf(zf[c][3], wv.w, ho[o]);
            }
        }
        #pragma unroll
        for (int m = 1; m < 64; m <<= 1) {
            #pragma unroll
            for (int o = 0; o < 10; ++o) ho[o] += __shfl_xor(ho[o], m);
        }
        if (lane == 0) {
            #pragma unroll
            for (int o = 0; o < 10; ++o) red[wid * 10 + o] = ho[o];
        }
    }
    __syncthreads();
    if (tid < 10)
        out[n * 10 + tid] = red[tid] + red[10 + tid] + red[20 + tid] + red[30 + tid] + bh[tid];
}

extern "C" void kernel_launch(void* const* d_in, const int* in_sizes, int n_in,
                              void* d_out, int out_size, void* d_ws, size_t ws_size,
                              hipStream_t stream) {
    const float* image = (const float*)d_in[0];
    const float* w1    = (const float*)d_in[1];
    const float* b1    = (const float*)d_in[2];
    const float* gam   = (const float*)d_in[3];
    const float* bet   = (const float*)d_in[4];
    const float* w2    = (const float*)d_in[5];
    const float* b2    = (const float*)d_in[6];
    const float* wh    = (const float*)d_in[7];
    const float* bh    = (const float*)d_in[8];
    float* out = (float*)d_out;
    unsigned* ws = (unsigned*)d_ws;

    pack_weights<<<5, 256, 0, stream>>>(w1, w2, ws);

    const int N = in_sizes[0] / (3 * 32 * 32);   // 1024 images
    deq_kernel<<<N, 256, 0, stream>>>(image, ws, b1, gam, bet, b2, wh, bh, out);
}

// Round 15
// 352.657 us; speedup vs baseline: 1.6761x; 1.0682x over previous
//
#include <hip/hip_runtime.h>
#include <hip/hip_fp16.h>

// DEQ classifier, dx-packed 16x16x32 MFMA with ROW-REUSE (dy-sharing).
// One block per image (1024 x 256 threads, 4 waves; wave owns 8 output rows
// with acc[8] held simultaneously). LDS: one carved buffer:
//   [0,5184)      zxb plane  (36x36 bundles of 8-ch f16, 16 B each)
//   [5184,10368)  hbb plane
//   [10368,12928) wl1: conv1 A-frags (10 chunks x 64 lanes x 4 dw)
//   [12928,15488) wl2: conv2 A-frags
// swizzle bofs(y,x)=((y*36+x)*16)^((x&8)<<1)  (bijective, R9-proven).
// Conv as MFMA 16x16x32 with ROW-REUSE:
//   chunk (ty,txh): A[16 rows=(dx*8+oc)][32 k=(tx=4*txh+tg, ch)] frag
//   ONE B-read = pixel bundles at row pr, x=2*col+tx  feeds MFMAs for all
//   output rows g = pr-ty (0<=g<8):  24 pixel b128/conv/wave instead of 64.
//   (tx=6,7 slots have zero A-weights; their reads land <=32B past the
//    plane, inside the following LDS region -- garbage * 0 = 0.)
//   D: col=lane&15=anchor, row=(lane>>4)*4+reg = dx*8+oc  (R9-verified)
// GroupNorm folded into conv2 (w2*sc at frag load, h-pads=-sh/sc,
// bias2' = b2 + S2*sh)  -- R9's proven scheme.
// launch_bounds(256,2) -> VGPR cap 128; est live ~110 (acc 32 + frags 40).
// Tripwire: FETCH_SIZE ~7 MB; spill shows as FETCH/WRITE blowup.

typedef _Float16 half8 __attribute__((ext_vector_type(8)));
typedef float f32x4 __attribute__((ext_vector_type(4)));

#define PLANE 5184              // dwords per pixel plane
#define HB    5184              // hbb dword offset
#define WL1   10368             // conv1 frag table dword offset
#define WL2   12928             // conv2 frag table dword offset
#define NLDS  15488             // total carved dwords

__device__ __forceinline__ unsigned pk2(float a, float b) {
    __half2 h = __float22half2_rn(make_float2(a, b));
    return *reinterpret_cast<unsigned*>(&h);
}
__device__ __forceinline__ float2 up2(unsigned u) {
    __half2 h = *reinterpret_cast<__half2*>(&u);
    return __half22float2(h);
}
__device__ __forceinline__ unsigned hmul2(unsigned a, unsigned b) {
    __half2 r = __hmul2(*reinterpret_cast<__half2*>(&a), *reinterpret_cast<__half2*>(&b));
    return *reinterpret_cast<unsigned*>(&r);
}
__device__ __forceinline__ float lrelu(float x) { return fmaxf(x, 0.01f * x); }
__device__ __forceinline__ int bofs(int y, int x) {
    return ((y * 36 + x) * 16) ^ ((x & 8) << 1);
}

// ---- prep: row-reuse A-fragments + tap-sum table ----
// ws[0..2559]    : conv1 frags, chunk c=(ty*2+txh), lane l:
//   row=l&15 (dx=row>>3, oc=row&7), tg=l>>4, tx=4*txh+tg, kx=tx-dx
//   elem pair d = ch (2d,2d+1): w1[oc][ch][ty][kx], 0 if oc>=6 or kx not in [0,5)
// ws[2560..5119] : conv2 frags from w2 (0 if oc>=5, ch>=6)
// ws[5120..5149] : S2[oc][ch] = sum_tap w2[oc][ch][tap]  (f32)
__global__ void pack_weights(const float* __restrict__ w1,
                             const float* __restrict__ w2,
                             unsigned* __restrict__ ws)
{
    int t = blockIdx.x * 256 + threadIdx.x;
    if (t < 640) {
        int c = t >> 6, l = t & 63;
        int row = l & 15, tg = l >> 4;
        int dx = row >> 3, oc = row & 7;
        int ty = c >> 1, tx = 4 * (c & 1) + tg, kx = tx - dx;
        unsigned q[4];
        #pragma unroll
        for (int d = 0; d < 4; ++d) {
            float v0 = 0.f, v1 = 0.f;
            if (oc < 6 && kx >= 0 && kx < 5) {
                v0 = w1[(oc * 8 + 2 * d) * 25 + ty * 5 + kx];
                v1 = w1[(oc * 8 + 2 * d + 1) * 25 + ty * 5 + kx];
            }
            q[d] = pk2(v0, v1);
        }
        *(uint4*)&ws[t * 4] = make_uint4(q[0], q[1], q[2], q[3]);
    } else if (t < 1280) {
        int u = t - 640;
        int c = u >> 6, l = u & 63;
        int row = l & 15, tg = l >> 4;
        int dx = row >> 3, oc = row & 7;
        int ty = c >> 1, tx = 4 * (c & 1) + tg, kx = tx - dx;
        unsigned q[4];
        #pragma unroll
        for (int d = 0; d < 4; ++d) {
            float v0 = 0.f, v1 = 0.f;
            if (oc < 5 && kx >= 0 && kx < 5) {
                if (2 * d < 6)     v0 = w2[(oc * 6 + 2 * d) * 25 + ty * 5 + kx];
                if (2 * d + 1 < 6) v1 = w2[(oc * 6 + 2 * d + 1) * 25 + ty * 5 + kx];
            }
            q[d] = pk2(v0, v1);
        }
        *(uint4*)&ws[2560 + u * 4] = make_uint4(q[0], q[1], q[2], q[3]);
    } else if (t < 1310) {
        int idx = t - 1280;
        int oc = idx / 6, ch = idx % 6;
        float s = 0.f;
        for (int tap = 0; tap < 25; ++tap) s += w2[(oc * 6 + ch) * 25 + tap];
        ((float*)ws)[5120 + idx] = s;
    }
}

__global__ __launch_bounds__(256, 2)
void deq_kernel(const float* __restrict__ image,
                const unsigned* __restrict__ wks,
                const float* __restrict__ b1,
                const float* __restrict__ gam, const float* __restrict__ bet,
                const float* __restrict__ b2,
                const float* __restrict__ wh, const float* __restrict__ bh,
                float* __restrict__ out)
{
    __shared__ __align__(16) unsigned lds[NLDS];
    __shared__ float red[48];
    __shared__ float s2s[32];

    const int n    = blockIdx.x;
    const int tid  = threadIdx.x;
    const int lane = tid & 63;
    const int wid  = tid >> 6;          // 0..3: wave owns output rows wid*8..+7
    const int col  = lane & 15;         // anchor: pixels 2col, 2col+1
    const int tg   = lane >> 4;
    const int dxl  = tg >> 1;           // this lane's output dx
    const int sub  = tg & 1;            // 0: ch0-3, 1: ch4-7

    for (int p = tid; p < 2 * PLANE; p += 256) lds[p] = 0u;
    for (int p = tid; p < 2560; p += 256) {
        lds[WL1 + p] = wks[p];
        lds[WL2 + p] = wks[2560 + p];
    }
    if (tid < 30) s2s[tid] = ((const float*)wks)[5120 + tid];
    __syncthreads();

    {   // image -> zx bundle ch 5..7 (each thread one 1x4 strip)
        const int yy = tid >> 3, xx0 = (tid & 7) << 2;
        float4 i0 = *(const float4*)&image[(n * 3 + 0) * 1024 + yy * 32 + xx0];
        float4 i1 = *(const float4*)&image[(n * 3 + 1) * 1024 + yy * 32 + xx0];
        float4 i2 = *(const float4*)&image[(n * 3 + 2) * 1024 + yy * 32 + xx0];
        float a0[4] = {i0.x, i0.y, i0.z, i0.w};
        float a1[4] = {i1.x, i1.y, i1.z, i1.w};
        float a2[4] = {i2.x, i2.y, i2.z, i2.w};
        #pragma unroll
        for (int i = 0; i < 4; ++i) {
            unsigned* bp = (unsigned*)((char*)lds + bofs(yy + 2, xx0 + 2 + i));
            bp[2] = pk2(0.f, a0[i]);
            bp[3] = pk2(a1[i], a2[i]);
        }
    }

    // per-lane x-offsets for the two tx-halves: x = 2*col + 4*txh + tg
    int sx2[2];
    #pragma unroll
    for (int txh = 0; txh < 2; ++txh) {
        int x = 2 * col + 4 * txh + tg;
        sx2[txh] = (x * 16) ^ ((x & 8) << 1);
    }

    float b1q[4], b2q[4];
    #pragma unroll
    for (int r = 0; r < 4; ++r) {
        int oc = (tg * 4 + r) & 7;
        b1q[r] = (oc < 6) ? b1[oc] : 0.f;
        b2q[r] = (oc < 5) ? b2[oc] : 0.f;
    }
    const f32x4 ai1 = {b1q[0], b1q[1], b1q[2], b1q[3]};

    __syncthreads();

    const char* zb  = (const char*)lds;
    const char* hbB = (const char*)lds + HB * 4;
    const int ay0 = wid << 3;           // wave owns output rows ay0..ay0+7
    const int wlo = lane << 2;          // lane's frag dword base within a chunk

    #pragma unroll 1
    for (int it = 0; it < 30; ++it) {
        // ================= conv1 (row-reuse: 24 B-reads, 80 MFMA) =================
        uint4 f1[10];
        #pragma unroll
        for (int c = 0; c < 10; ++c)
            f1[c] = *(const uint4*)&lds[WL1 + c * 256 + wlo];

        f32x4 acc[8];
        #pragma unroll
        for (int g = 0; g < 8; ++g) acc[g] = ai1;

        #pragma unroll
        for (int pr = 0; pr < 12; ++pr) {
            const char* rowp = zb + (ay0 + pr) * 576;
            #pragma unroll
            for (int txh = 0; txh < 2; ++txh) {
                half8 pv = *(const half8*)(rowp + sx2[txh]);
                #pragma unroll
                for (int ty = 0; ty < 5; ++ty) {
                    const int g = pr - ty;
                    if (g >= 0 && g < 8)
                        acc[g] = __builtin_amdgcn_mfma_f32_16x16x32_f16(
                            __builtin_bit_cast(half8, f1[ty * 2 + txh]), pv, acc[g], 0, 0, 0);
                }
            }
        }

        // ---- leaky + h write + GN partial stats ----
        float ps_lo = 0.f, ps_hi = 0.f, pq_lo = 0.f, pq_hi = 0.f;
        #pragma unroll
        for (int g = 0; g < 8; ++g) {
            float h0 = lrelu(acc[g][0]), h1 = lrelu(acc[g][1]);
            float h2 = lrelu(acc[g][2]), h3 = lrelu(acc[g][3]);
            ps_lo += h0 + h1;  pq_lo = fmaf(h0, h0, fmaf(h1, h1, pq_lo));
            ps_hi += h2 + h3;  pq_hi = fmaf(h2, h2, fmaf(h3, h3, pq_hi));
            char* wp = (char*)lds + HB * 4 + bofs(ay0 + g + 2, 2 * col + dxl + 2) + sub * 8;
            *(uint2*)wp = make_uint2(pk2(h0, h1), pk2(h2, h3));
        }

        // GN stats reduce: anchors (xor 1..8) then dx halves (xor 32)
        #pragma unroll
        for (int m = 1; m <= 8; m <<= 1) {
            ps_lo += __shfl_xor(ps_lo, m); ps_hi += __shfl_xor(ps_hi, m);
            pq_lo += __shfl_xor(pq_lo, m); pq_hi += __shfl_xor(pq_hi, m);
        }
        ps_lo += __shfl_xor(ps_lo, 32); ps_hi += __shfl_xor(ps_hi, 32);
        pq_lo += __shfl_xor(pq_lo, 32); pq_hi += __shfl_xor(pq_hi, 32);
        if (lane == 0)  { red[wid * 8 + 0] = ps_lo; red[wid * 8 + 1] = ps_hi;
                          red[wid * 8 + 4] = pq_lo; red[wid * 8 + 5] = pq_hi; }
        if (lane == 16) { red[wid * 8 + 2] = ps_lo; red[wid * 8 + 6] = pq_lo; }
        __syncthreads();                               // B1

        // ---- fold GN into conv2 operands ----
        float scv[6], shv[6];
        #pragma unroll
        for (int g3 = 0; g3 < 3; ++g3) {
            float s = 0.f, q = 0.f;
            #pragma unroll
            for (int w = 0; w < 4; ++w) { s += red[w * 8 + g3]; q += red[w * 8 + 4 + g3]; }
            float mean = s * (1.f / 2048.f);
            float var  = q * (1.f / 2048.f) - mean * mean;
            float inv  = rsqrtf(var + 1e-5f);
            #pragma unroll
            for (int k = 0; k < 2; ++k) {
                int c = 2 * g3 + k;
                scv[c] = inv * gam[c];
                shv[c] = bet[c] - mean * scv[c];
            }
        }
        f32x4 ai2;
        #pragma unroll
        for (int r = 0; r < 4; ++r) {
            int ocr = (tg * 4 + r) & 7;
            int base = (ocr < 5) ? ocr * 6 : 0;
            float db = 0.f;
            #pragma unroll
            for (int ch = 0; ch < 6; ++ch) db = fmaf(s2s[base + ch], shv[ch], db);
            ai2[r] = b2q[r] + ((ocr < 5) ? db : 0.f);
        }
        unsigned sp0 = pk2(scv[0], scv[1]), sp1 = pk2(scv[2], scv[3]), sp2 = pk2(scv[4], scv[5]);
        // h pads <- -sh/sc
        {
            float ph[6];
            #pragma unroll
            for (int c = 0; c < 6; ++c) {
                float rs = (fabsf(scv[c]) > 1e-20f) ? 1.f / scv[c] : 0.f;
                ph[c] = -shv[c] * rs;
            }
            uint4 padq = make_uint4(pk2(ph[0], ph[1]), pk2(ph[2], ph[3]), pk2(ph[4], ph[5]), 0u);
            for (int t = tid; t < 272; t += 256) {
                int row, cc;
                if (t < 72)       { row = t / 36;             cc = t % 36; }
                else if (t < 144) { row = 34 + (t - 72) / 36; cc = (t - 72) % 36; }
                else {
                    int q4 = t - 144;
                    row = 2 + (q4 >> 2);
                    int c4 = q4 & 3;
                    cc = (c4 < 2) ? c4 : c4 + 32;
                }
                *(uint4*)((char*)lds + HB * 4 + bofs(row, cc)) = padq;
            }
        }
        __syncthreads();                               // B2

        // ============ conv2 (row-reuse; frags from LDS, scaled at load) ============
        uint4 f2[10];
        #pragma unroll
        for (int c = 0; c < 10; ++c) {
            uint4 wr = *(const uint4*)&lds[WL2 + c * 256 + wlo];
            f2[c].x = hmul2(wr.x, sp0);
            f2[c].y = hmul2(wr.y, sp1);
            f2[c].z = hmul2(wr.z, sp2);
            f2[c].w = 0u;
        }
        #pragma unroll
        for (int g = 0; g < 8; ++g) acc[g] = ai2;

        #pragma unroll
        for (int pr = 0; pr < 12; ++pr) {
            const char* rowp = hbB + (ay0 + pr) * 576;
            #pragma unroll
            for (int txh = 0; txh < 2; ++txh) {
                half8 pv = *(const half8*)(rowp + sx2[txh]);
                #pragma unroll
                for (int ty = 0; ty < 5; ++ty) {
                    const int g = pr - ty;
                    if (g >= 0 && g < 8)
                        acc[g] = __builtin_amdgcn_mfma_f32_16x16x32_f16(
                            __builtin_bit_cast(half8, f2[ty * 2 + txh]), pv, acc[g], 0, 0, 0);
                }
            }
        }

        // ---- leaky + damped z RMW ----
        #pragma unroll
        for (int g = 0; g < 8; ++g) {
            char* zp = (char*)lds + bofs(ay0 + g + 2, 2 * col + dxl + 2);
            if (sub == 0) {       // z0..z3: b64 RMW
                uint2 zo = *(uint2*)zp;
                float2 za = up2(zo.x), zc = up2(zo.y);
                float z0 = 0.5f * za.x + 0.5f * lrelu(acc[g][0]);
                float z1 = 0.5f * za.y + 0.5f * lrelu(acc[g][1]);
                float z2 = 0.5f * zc.x + 0.5f * lrelu(acc[g][2]);
                float z3 = 0.5f * zc.y + 0.5f * lrelu(acc[g][3]);
                *(uint2*)zp = make_uint2(pk2(z0, z1), pk2(z2, z3));
            } else {              // z4: u16 RMW (img0 in hi half untouched)
                _Float16* pz = (_Float16*)(zp + 8);
                float z4 = 0.5f * (float)pz[0] + 0.5f * lrelu(acc[g][0]);
                pz[0] = (_Float16)z4;
            }
        }
        __syncthreads();                               // B3
    }

    // ================= head: out[o] = <z, wh[o]> + bh[o] =================
    {
        const int yy = tid >> 3, xx0 = (tid & 7) << 2;
        float zf[5][4];
        #pragma unroll
        for (int i = 0; i < 4; ++i) {
            const unsigned* bp = (const unsigned*)((const char*)lds + bofs(yy + 2, xx0 + 2 + i));
            float2 f0 = up2(bp[0]), f1 = up2(bp[1]), f2 = up2(bp[2]);
            zf[0][i] = f0.x; zf[1][i] = f0.y; zf[2][i] = f1.x; zf[3][i] = f1.y; zf[4][i] = f2.x;
        }
        float ho[10];
        #pragma unroll
        for (int o = 0; o < 10; ++o) ho[o] = 0.f;
        #pragma unroll
        for (int c = 0; c < 5; ++c) {
            #pragma unroll
            for (int o = 0; o < 10; ++o) {
                float4 wv = *(const float4*)&wh[(o * 5 + c) * 1024 + yy * 32 + xx0];
                ho[o] = fmaf(zf[c][0], wv.x, ho[o]);
                ho[o] = fmaf(zf[c][1], wv.y, ho[o]);
                ho[o] = fmaf(zf[c][2], wv.z, ho[o]);
                ho[o] = fmaf(zf[c][3], wv.w, ho[o]);
            }
        }
        #pragma unroll
        for (int m = 1; m < 64; m <<= 1) {
            #pragma unroll
            for (int o = 0; o < 10; ++o) ho[o] += __shfl_xor(ho[o], m);
        }
        if (lane == 0) {
            #pragma unroll
            for (int o = 0; o < 10; ++o) red[wid * 10 + o] = ho[o];
        }
    }
    __syncthreads();
    if (tid < 10)
        out[n * 10 + tid] = red[tid] + red[10 + tid] + red[20 + tid] + red[30 + tid] + bh[tid];
}

extern "C" void kernel_launch(void* const* d_in, const int* in_sizes, int n_in,
                              void* d_out, int out_size, void* d_ws, size_t ws_size,
                              hipStream_t stream) {
    const float* image = (const float*)d_in[0];
    const float* w1    = (const float*)d_in[1];
    const float* b1    = (const float*)d_in[2];
    const float* gam   = (const float*)d_in[3];
    const float* bet   = (const float*)d_in[4];
    const float* w2    = (const float*)d_in[5];
    const float* b2    = (const float*)d_in[6];
    const float* wh    = (const float*)d_in[7];
    const float* bh    = (const float*)d_in[8];
    float* out = (float*)d_out;
    unsigned* ws = (unsigned*)d_ws;

    pack_weights<<<6, 256, 0, stream>>>(w1, w2, ws);

    const int N = in_sizes[0] / (3 * 32 * 32);   // 1024 images
    deq_kernel<<<N, 256, 0, stream>>>(image, ws, b1, gam, bet, b2, wh, bh, out);
}